// Round 1
// baseline (4907.139 us; speedup 1.0000x reference)
//
#include <hip/hip_runtime.h>

// TopK SAE: recon, codes = decode(topk(x @ W_enc + b_enc, k)) @ W_dec + b_dec
// B=16384, D_IN=768, D_SAE=12288, K=40. All fp32.
//
// Round 1 strategy: correctness-first fp32 baseline.
//  - Encode GEMM on vector ALU (no fp32 MFMA on CDNA4), 128x128 tiles.
//  - h staged through d_ws in row chunks.
//  - Fused topk+decode: 1 block/row, threshold prefilter + O(C^2) rank select.

#define DIN 768
#define DS  12288
#define NB  16384

// ---------------------------------------------------------------------------
// Encode GEMM: H[r, c] = sum_k A[r,k] * Bm[k,c] + bias[c]
// 128x128 tile, K-tile 16, 256 threads, 8x8 accumulators per thread.
// ---------------------------------------------------------------------------
__global__ __launch_bounds__(256)
void sae_encode_gemm(const float* __restrict__ A,    // chunkRows x DIN
                     const float* __restrict__ Bm,   // DIN x DS
                     const float* __restrict__ bias, // DS
                     float* __restrict__ H)          // chunkRows x DS
{
    __shared__ float As[16][132];   // [k][row], padded 132 to break conflicts
    __shared__ float Bs[16][132];   // [k][col]

    const int tid = threadIdx.x;
    const int tx = tid & 15;   // col group 0..15
    const int ty = tid >> 4;   // row group 0..15
    const int rowBase = blockIdx.y * 128;
    const int colBase = blockIdx.x * 128;

    float acc[8][8];
#pragma unroll
    for (int i = 0; i < 8; ++i)
#pragma unroll
        for (int j = 0; j < 8; ++j) acc[i][j] = 0.f;

    for (int kt = 0; kt < DIN; kt += 16) {
        // A tile: 128 rows x 16 k = 512 float4 loads (row-major, coalesced)
#pragma unroll
        for (int l = 0; l < 2; ++l) {
            int id = tid + l * 256;
            int r  = id >> 2;          // 0..127
            int kq = (id & 3) << 2;    // 0,4,8,12
            const float4 v = *(const float4*)(A + (size_t)(rowBase + r) * DIN + kt + kq);
            As[kq + 0][r] = v.x; As[kq + 1][r] = v.y;
            As[kq + 2][r] = v.z; As[kq + 3][r] = v.w;
        }
        // B tile: 16 k x 128 cols = 512 float4 loads (row-major, coalesced)
#pragma unroll
        for (int l = 0; l < 2; ++l) {
            int id = tid + l * 256;
            int kr = id >> 5;          // 0..15
            int c  = (id & 31) << 2;   // 0..124
            const float4 v = *(const float4*)(Bm + (size_t)(kt + kr) * DS + colBase + c);
            *(float4*)&Bs[kr][c] = v;
        }
        __syncthreads();
#pragma unroll
        for (int k = 0; k < 16; ++k) {
            float a[8], b[8];
            *(float4*)&a[0] = *(const float4*)&As[k][ty * 8];
            *(float4*)&a[4] = *(const float4*)&As[k][ty * 8 + 4];
            *(float4*)&b[0] = *(const float4*)&Bs[k][tx * 8];
            *(float4*)&b[4] = *(const float4*)&Bs[k][tx * 8 + 4];
#pragma unroll
            for (int i = 0; i < 8; ++i)
#pragma unroll
                for (int j = 0; j < 8; ++j)
                    acc[i][j] = fmaf(a[i], b[j], acc[i][j]);
        }
        __syncthreads();
    }

    float bvals[8];
    *(float4*)&bvals[0] = *(const float4*)(bias + colBase + tx * 8);
    *(float4*)&bvals[4] = *(const float4*)(bias + colBase + tx * 8 + 4);
#pragma unroll
    for (int i = 0; i < 8; ++i) {
        size_t off = (size_t)(rowBase + ty * 8 + i) * DS + colBase + tx * 8;
        float4 o0 = make_float4(acc[i][0] + bvals[0], acc[i][1] + bvals[1],
                                acc[i][2] + bvals[2], acc[i][3] + bvals[3]);
        float4 o1 = make_float4(acc[i][4] + bvals[4], acc[i][5] + bvals[5],
                                acc[i][6] + bvals[6], acc[i][7] + bvals[7]);
        *(float4*)(H + off)     = o0;
        *(float4*)(H + off + 4) = o1;
    }
}

// ---------------------------------------------------------------------------
// Fused top-k + codes write + sparse decode. One 256-thread block per row.
//  1. prefilter h > T into LDS candidate list (T=2.2 -> ~171 candidates;
//     retry loop lowers T if fewer than k — statistically never fires)
//  2. O(C^2) rank select: rank < k  => selected (tie-break lower index)
//  3. write codes row: zeros + scattered relu(vals)
//  4. recon[row,:] = sum_t val_t * W_dec[idx_t,:] + b_dec
// ---------------------------------------------------------------------------
#define CAP 1024

__global__ __launch_bounds__(256)
void sae_topk_decode(const float* __restrict__ Hc,   // chunkRows x DS
                     const float* __restrict__ Wdec, // DS x DIN
                     const float* __restrict__ bdec, // DIN
                     const int* __restrict__ kp,
                     float* __restrict__ recon,      // NB x DIN (global)
                     float* __restrict__ codes,      // NB x DS  (global)
                     int rowOffset)
{
    const int tid  = threadIdx.x;
    const int lrow = blockIdx.x;
    const int row  = rowOffset + lrow;
    const float* hrow = Hc + (size_t)lrow * DS;

    __shared__ float cval[CAP];
    __shared__ int   cidx[CAP];
    __shared__ float sval[64];
    __shared__ int   sidx[64];
    __shared__ int   cnt, scnt;

    int K = *kp;
    if (K > 64) K = 64;
    if (K < 1)  K = 1;

    // row resident in registers: 48 strided coalesced loads
    float local[48];
#pragma unroll
    for (int s = 0; s < 48; ++s) local[s] = hrow[tid + (s << 8)];

    float T = 2.2f;
    for (int iter = 0;; ++iter) {
        if (tid == 0) cnt = 0;
        __syncthreads();
#pragma unroll
        for (int s = 0; s < 48; ++s) {
            if (local[s] > T) {
                int p = atomicAdd(&cnt, 1);
                if (p < CAP) { cval[p] = local[s]; cidx[p] = tid + (s << 8); }
            }
        }
        __syncthreads();
        if (cnt >= K || iter >= 8) break;
        T -= 1.5f;
        __syncthreads();
    }
    const int C = cnt < CAP ? cnt : CAP;

    if (tid == 0) scnt = 0;
    __syncthreads();

    // rank select (set semantics — order of sval/sidx is irrelevant)
    for (int p = tid; p < C; p += 256) {
        float v = cval[p];
        int   id = cidx[p];
        int rank = 0;
        for (int q = 0; q < C; ++q) {
            float u = cval[q];
            rank += (u > v) || (u == v && cidx[q] < id);
        }
        if (rank < K) {
            int s = atomicAdd(&scnt, 1);
            sval[s] = v > 0.f ? v : 0.f;   // relu
            sidx[s] = id;
        }
    }
    __syncthreads();
    int S = scnt;
    if (S > K) S = K;

    // codes row: zero-fill then scatter
    float* crow = codes + (size_t)row * DS;
    const float4 z4 = make_float4(0.f, 0.f, 0.f, 0.f);
    for (int p = tid; p < DS / 4; p += 256) ((float4*)crow)[p] = z4;
    __syncthreads();
    if (tid < S) crow[sidx[tid]] = sval[tid];

    // sparse decode: 768 cols over 256 threads (3 each, coalesced)
    float a0 = bdec[tid], a1 = bdec[tid + 256], a2 = bdec[tid + 512];
    for (int t = 0; t < S; ++t) {
        float v = sval[t];
        const float* wr = Wdec + (size_t)sidx[t] * DIN;
        a0 = fmaf(v, wr[tid],       a0);
        a1 = fmaf(v, wr[tid + 256], a1);
        a2 = fmaf(v, wr[tid + 512], a2);
    }
    float* rrow = recon + (size_t)row * DIN;
    rrow[tid]       = a0;
    rrow[tid + 256] = a1;
    rrow[tid + 512] = a2;
}

// ---------------------------------------------------------------------------
extern "C" void kernel_launch(void* const* d_in, const int* in_sizes, int n_in,
                              void* d_out, int out_size, void* d_ws, size_t ws_size,
                              hipStream_t stream)
{
    const float* x    = (const float*)d_in[0];
    const float* Wenc = (const float*)d_in[1];
    const float* benc = (const float*)d_in[2];
    const float* Wdec = (const float*)d_in[3];
    const float* bdec = (const float*)d_in[4];
    const int*   kp   = (const int*)d_in[5];

    float* recon = (float*)d_out;                         // NB x DIN
    float* codes = (float*)d_out + (size_t)NB * DIN;      // NB x DS
    float* Hws   = (float*)d_ws;

    // chunk rows so h-chunk fits in workspace (multiple of 128)
    size_t rowBytes = (size_t)DS * sizeof(float);
    size_t maxRows  = ws_size / rowBytes;
    int CH = (int)(maxRows > NB ? NB : maxRows);
    CH &= ~127;
    if (CH <= 0) CH = 128;

    for (int off = 0; off < NB; off += CH) {
        int rows = NB - off;
        if (rows > CH) rows = CH;
        dim3 ggrid(DS / 128, rows / 128);
        sae_encode_gemm<<<ggrid, 256, 0, stream>>>(x + (size_t)off * DIN, Wenc, benc, Hws);
        sae_topk_decode<<<rows, 256, 0, stream>>>(Hws, Wdec, bdec, kp, recon, codes, off);
    }
}

// Round 2
// 2723.025 us; speedup vs baseline: 1.8021x; 1.8021x over previous
//
#include <hip/hip_runtime.h>

// TopK SAE, round 2: bf16-split MFMA encode + exact boundary rescue.
// h = x@W_enc + b_enc computed as h~ = x_hi*w_hi + x_hi*w_lo + x_lo*w_hi
// (single bf16 MFMA GEMM, K'=2304, fp32 accumulate; |h~ - h| <= ~2e-4).
// Top-k selection: elements with h~ > v40+MARGIN are definitely selected;
// elements within +-MARGIN of v40 get exact fp32 recompute (sequential fma,
// bit-identical to round 1's accumulation order, which passed).

#define DIN 768
#define DS  12288
#define NB  16384
#define KP  2304          // 3*768 split-K
#define MARGIN 1e-3f
#define CAP 1024

typedef unsigned short u16;
typedef __attribute__((ext_vector_type(8))) short bf8_t;   // 8 bf16 = 4 VGPRs
typedef __attribute__((ext_vector_type(4))) float f4_t;

__device__ __forceinline__ u16 f2bf(float f) {            // round-nearest-even
    union { float f; unsigned u; } v; v.f = f;
    unsigned r = v.u + 0x7fffu + ((v.u >> 16) & 1u);
    return (u16)(r >> 16);
}
__device__ __forceinline__ float bf2f(u16 h) {
    union { unsigned u; float f; } v; v.u = ((unsigned)h) << 16;
    return v.f;
}

// ---------------------------------------------------------------------------
// split x rows into A' (rows x 2304 bf16): [hi | hi | lo]
// ---------------------------------------------------------------------------
__global__ __launch_bounds__(256)
void split_x(const float* __restrict__ x, u16* __restrict__ A)
{
    const int r = blockIdx.x, k = blockIdx.y * 256 + threadIdx.x;
    float v = x[(size_t)r * DIN + k];
    u16 h = f2bf(v);
    u16 l = f2bf(v - bf2f(h));
    u16* ar = A + (size_t)r * KP;
    ar[k] = h; ar[768 + k] = h; ar[1536 + k] = l;
}

// ---------------------------------------------------------------------------
// W_enc (768 x 12288) -> Bst (12288 x 2304 bf16, n-major): [hi | lo | hi]
//                     -> WencT (12288 x 768 fp32) for exact recompute
// ---------------------------------------------------------------------------
__global__ __launch_bounds__(256)
void split_w(const float* __restrict__ W, u16* __restrict__ Bst,
             float* __restrict__ Wt)
{
    __shared__ float tile[64][65];
    const int n0 = blockIdx.x * 64, k0 = blockIdx.y * 64;
    const int t = threadIdx.x;
    const int cn = t & 63, rk = t >> 6;
#pragma unroll
    for (int i = 0; i < 16; ++i)
        tile[rk + i * 4][cn] = W[(size_t)(k0 + rk + i * 4) * DS + n0 + cn];
    __syncthreads();
    const int nl = t >> 2, kc = (t & 3) * 16;
    u16*   bb = Bst + (size_t)(n0 + nl) * KP + k0;
    float* tb = Wt  + (size_t)(n0 + nl) * DIN + k0;
#pragma unroll
    for (int j = 0; j < 16; ++j) {
        int kl = kc + j;
        float v = tile[kl][nl];
        u16 h = f2bf(v), l = f2bf(v - bf2f(h));
        bb[kl] = h; bb[768 + kl] = l; bb[1536 + kl] = h;
        tb[kl] = v;
    }
}

// ---------------------------------------------------------------------------
// MFMA GEMM: H~ (rows x 12288 fp32) = A'(rows x 2304) * Bst^T + bias
// 128x128 tile, BK=64, 4 waves, 16x16x32 bf16 MFMA, global_load_lds(16B),
// XOR-swizzled LDS chunks (position p of row m holds k-chunk p^(m&7)).
// ---------------------------------------------------------------------------
__global__ __launch_bounds__(256)
void sae_gemm(const u16* __restrict__ A,   // rows x KP
              const u16* __restrict__ B,   // DS x KP (n-major)
              const float* __restrict__ bias,
              float* __restrict__ H)
{
    __shared__ __align__(16) u16 Asl[128 * 64];
    __shared__ __align__(16) u16 Bsl[128 * 64];

    const int tid  = threadIdx.x;
    const int lane = tid & 63;
    const int wave = tid >> 6;
    const int wr = wave >> 1, wc = wave & 1;
    const int rowBase = blockIdx.y * 128;
    const int colBase = blockIdx.x * 128;

    // staging addressing: lane covers LDS bytes [grpBase + lane*16)
    const int l8    = lane >> 3;          // row within 8-row group == m&7
    const int c_pos = lane & 7;           // LDS chunk position
    const int c_dat = c_pos ^ l8;         // global k-chunk stored there

    const u16* agp[4];  const u16* bgp[4];
    const u16* alp[4];  const u16* blp[4];
#pragma unroll
    for (int i = 0; i < 4; ++i) {
        int m = wave * 32 + i * 8;
        agp[i] = A + (size_t)(rowBase + m + l8) * KP + c_dat * 8;
        bgp[i] = B + (size_t)(colBase + m + l8) * KP + c_dat * 8;
        alp[i] = &Asl[m * 64];
        blp[i] = &Bsl[m * 64];
    }

    f4_t acc[4][4];
#pragma unroll
    for (int i = 0; i < 4; ++i)
#pragma unroll
        for (int j = 0; j < 4; ++j) acc[i][j] = (f4_t)0.f;

    const int quad = lane >> 4;
    const int r16  = lane & 15;

    for (int kt = 0; kt < KP; kt += 64) {
        __syncthreads();
#pragma unroll
        for (int i = 0; i < 4; ++i) {
            __builtin_amdgcn_global_load_lds(
                (const __attribute__((address_space(1))) void*)(const void*)(agp[i] + kt),
                (__attribute__((address_space(3))) void*)(void*)alp[i], 16, 0, 0);
            __builtin_amdgcn_global_load_lds(
                (const __attribute__((address_space(1))) void*)(const void*)(bgp[i] + kt),
                (__attribute__((address_space(3))) void*)(void*)blp[i], 16, 0, 0);
        }
        __syncthreads();
#pragma unroll
        for (int kk = 0; kk < 2; ++kk) {
            bf8_t af[4], bfr[4];
            int cd = kk * 4 + quad;
#pragma unroll
            for (int i = 0; i < 4; ++i) {
                int m = wr * 64 + i * 16 + r16;
                af[i] = *(const bf8_t*)&Asl[m * 64 + ((cd ^ (m & 7)) << 3)];
                int n = wc * 64 + i * 16 + r16;
                bfr[i] = *(const bf8_t*)&Bsl[n * 64 + ((cd ^ (n & 7)) << 3)];
            }
#pragma unroll
            for (int i = 0; i < 4; ++i)
#pragma unroll
                for (int j = 0; j < 4; ++j)
                    acc[i][j] = __builtin_amdgcn_mfma_f32_16x16x32_bf16(
                        af[i], bfr[j], acc[i][j], 0, 0, 0);
        }
    }

    // epilogue: D[row=quad*4+r][col=lane&15] per 16x16 frag, + bias
#pragma unroll
    for (int j = 0; j < 4; ++j) {
        int col = colBase + wc * 64 + j * 16 + r16;
        float bv = bias[col];
#pragma unroll
        for (int i = 0; i < 4; ++i) {
            int rbase = rowBase + wr * 64 + i * 16 + quad * 4;
#pragma unroll
            for (int rr = 0; rr < 4; ++rr)
                H[(size_t)(rbase + rr) * DS + col] = acc[i][j][rr] + bv;
        }
    }
}

// ---------------------------------------------------------------------------
// topk + boundary rescue + codes + sparse decode. One 256-thread block/row.
// ---------------------------------------------------------------------------
__global__ __launch_bounds__(256)
void sae_topk_decode(const float* __restrict__ Hc,    // chunkRows x DS (h~)
                     const float* __restrict__ x,     // NB x DIN
                     const float* __restrict__ WencT, // DS x DIN
                     const float* __restrict__ benc,
                     const float* __restrict__ Wdec,  // DS x DIN
                     const float* __restrict__ bdec,
                     const int* __restrict__ kp,
                     float* __restrict__ recon,
                     float* __restrict__ codes,
                     int rowOffset)
{
    const int tid  = threadIdx.x;
    const int lrow = blockIdx.x;
    const int row  = rowOffset + lrow;
    const float* hrow = Hc + (size_t)lrow * DS;

    __shared__ float cval[CAP];
    __shared__ int   cidx[CAP];
    __shared__ float xs[DIN];
    __shared__ float sval[64];  __shared__ int sidx[64];
    __shared__ float bex[64];   __shared__ int bidx[64];
    __shared__ int cnt, selc, bandc;
    __shared__ float sh_v40;

    int K = *kp;
    if (K > 64) K = 64;
    if (K < 1)  K = 1;

    // stage x row for recompute
    xs[tid]       = x[(size_t)row * DIN + tid];
    xs[tid + 256] = x[(size_t)row * DIN + tid + 256];
    xs[tid + 512] = x[(size_t)row * DIN + tid + 512];

    float local[48];
#pragma unroll
    for (int s = 0; s < 48; ++s) local[s] = hrow[tid + (s << 8)];

    float T = 2.0f, v40 = 0.f;
    for (int iter = 0; iter < 8; ++iter) {
        if (tid == 0) cnt = 0;
        __syncthreads();
#pragma unroll
        for (int s = 0; s < 48; ++s) {
            if (local[s] > T) {
                int p = atomicAdd(&cnt, 1);
                if (p < CAP) { cval[p] = local[s]; cidx[p] = tid + (s << 8); }
            }
        }
        __syncthreads();
        int C = cnt < CAP ? cnt : CAP;
        if (C < K) { T -= 1.0f; __syncthreads(); continue; }
        for (int p = tid; p < C; p += 256) {       // rank -> find K-th value
            float v = cval[p]; int id = cidx[p]; int rank = 0;
            for (int q = 0; q < C; ++q) {
                float u = cval[q];
                rank += (u > v) || (u == v && cidx[q] < id);
            }
            if (rank == K - 1) sh_v40 = v;
        }
        __syncthreads();
        v40 = sh_v40;
        if (v40 - 2.1f * MARGIN <= T) { T = v40 - 4.f * MARGIN; __syncthreads(); continue; }
        break;
    }

    if (tid == 0) { selc = 0; bandc = 0; }
    __syncthreads();
    const int C = cnt < CAP ? cnt : CAP;
    const float hiB = v40 + MARGIN, loB = v40 - MARGIN;
    for (int p = tid; p < C; p += 256) {
        float v = cval[p];
        if (v > hiB) {                    // definitely in top-K: keep h~ value
            int s = atomicAdd(&selc, 1);
            if (s < 64) { sval[s] = v > 0.f ? v : 0.f; sidx[s] = cidx[p]; }
        } else if (v >= loB) {            // boundary band: needs exact value
            int b = atomicAdd(&bandc, 1);
            if (b < 64) bidx[b] = cidx[p];
        }
    }
    __syncthreads();
    int m1 = selc; if (m1 > K) m1 = K;
    int nb = bandc; if (nb > 64) nb = 64;
    int need = K - m1; if (need < 0) need = 0;

    // exact recompute, bit-identical order to round-1 (sequential fma + bias)
    if (tid < nb) {
        const float* wrp = WencT + (size_t)bidx[tid] * DIN;
        float a = 0.f;
        for (int k2 = 0; k2 < DIN; ++k2) a = fmaf(xs[k2], wrp[k2], a);
        bex[tid] = a + benc[bidx[tid]];
    }
    __syncthreads();
    if (tid < nb) {                       // top-need among band by exact value
        float v = bex[tid]; int id = bidx[tid]; int rank = 0;
        for (int q = 0; q < nb; ++q) {
            float u = bex[q];
            rank += (u > v) || (u == v && bidx[q] < id);
        }
        if (rank < need) {
            int s = atomicAdd(&selc, 1);
            if (s < 64) { sval[s] = v > 0.f ? v : 0.f; sidx[s] = id; }
        }
    }
    __syncthreads();
    int S = selc; if (S > K) S = K; if (S > 64) S = 64;

    // codes row: zero-fill + scatter
    float* crow = codes + (size_t)row * DS;
    const float4 z4 = make_float4(0.f, 0.f, 0.f, 0.f);
    for (int p = tid; p < DS / 4; p += 256) ((float4*)crow)[p] = z4;
    __syncthreads();
    if (tid < S) crow[sidx[tid]] = sval[tid];

    // sparse decode
    float a0 = bdec[tid], a1 = bdec[tid + 256], a2 = bdec[tid + 512];
    for (int t = 0; t < S; ++t) {
        float v = sval[t];
        const float* wrp = Wdec + (size_t)sidx[t] * DIN;
        a0 = fmaf(v, wrp[tid],       a0);
        a1 = fmaf(v, wrp[tid + 256], a1);
        a2 = fmaf(v, wrp[tid + 512], a2);
    }
    float* rrow = recon + (size_t)row * DIN;
    rrow[tid]       = a0;
    rrow[tid + 256] = a1;
    rrow[tid + 512] = a2;
}

// ---------------------------------------------------------------------------
extern "C" void kernel_launch(void* const* d_in, const int* in_sizes, int n_in,
                              void* d_out, int out_size, void* d_ws, size_t ws_size,
                              hipStream_t stream)
{
    const float* x    = (const float*)d_in[0];
    const float* Wenc = (const float*)d_in[1];
    const float* benc = (const float*)d_in[2];
    const float* Wdec = (const float*)d_in[3];
    const float* bdec = (const float*)d_in[4];
    const int*   kp   = (const int*)d_in[5];

    float* recon = (float*)d_out;
    float* codes = recon + (size_t)NB * DIN;

    char* ws = (char*)d_ws;
    const size_t BST_B   = (size_t)DS * KP * 2;       //  56,623,104
    const size_t WENCT_B = (size_t)DS * DIN * 4;      //  37,748,736
    u16*   Bst   = (u16*)ws;
    float* WencT = (float*)(ws + BST_B);
    char*  dyn   = ws + BST_B + WENCT_B;

    const size_t perRow = (size_t)KP * 2 + (size_t)DS * 4;   // 53,760 B
    long long availRows = (long long)(ws_size - (BST_B + WENCT_B)) / (long long)perRow;
    int CH = availRows > NB ? NB : (int)availRows;
    CH &= ~127;
    if (CH > 8192) CH = 8192;
    if (CH < 128)  CH = 128;

    u16*   Axp = (u16*)dyn;
    float* Hws = (float*)(dyn + (size_t)CH * KP * 2);

    split_w<<<dim3(DS / 64, DIN / 64), 256, 0, stream>>>(Wenc, Bst, WencT);

    for (int off = 0; off < NB; off += CH) {
        int rows = NB - off;
        if (rows > CH) rows = CH;
        split_x<<<dim3(rows, 3), 256, 0, stream>>>(x + (size_t)off * DIN, Axp);
        sae_gemm<<<dim3(DS / 128, rows / 128), 256, 0, stream>>>(Axp, Bst, benc, Hws);
        sae_topk_decode<<<rows, 256, 0, stream>>>(Hws, x, WencT, benc, Wdec, bdec,
                                                  kp, recon, codes, off);
    }
}